// Round 1
// baseline (1342.638 us; speedup 1.0000x reference)
//
#include <hip/hip_runtime.h>
#include <hip/hip_bf16.h>

#define T_LEN 2048
#define B_SZ  64
#define D_IN  64
#define H_SZ  128

// ---------------------------------------------------------------------------
// Kernel 1: collapse fc1+fc2 (no nonlinearity between them) into
//   w_eff[i] = sum_o fc2_W[o] * fc1_W[o, i]   (i in [0,256))
//   b_eff    = sum_o fc2_W[o] * fc1_b[o] + fc2_b
// ws layout (floats): [0..255]=w_eff, [256]=b_eff, [512..]=partials
// ---------------------------------------------------------------------------
__global__ __launch_bounds__(256)
void prep_kernel(const float* __restrict__ fc1_W, const float* __restrict__ fc1_b,
                 const float* __restrict__ fc2_W, const float* __restrict__ fc2_b,
                 float* __restrict__ ws)
{
    const int i = threadIdx.x;  // 0..255
    float s = 0.0f;
    #pragma unroll 4
    for (int o = 0; o < 128; ++o) s = fmaf(fc2_W[o], fc1_W[o * 256 + i], s);
    ws[i] = s;

    __shared__ float red[128];
    if (i < 128) red[i] = fc2_W[i] * fc1_b[i];
    __syncthreads();
    if (i == 0) {
        float b = fc2_b[0];
        for (int o = 0; o < 128; ++o) b += red[o];
        ws[256] = b;
    }
}

// ---------------------------------------------------------------------------
// Kernel 2: fused input-projection + ReLU recurrence + logit partial dot.
// One block per (dir, batch) chain: 128 blocks, 256 threads.
// Thread (w = tid>>6, l = tid&63): output j = w*32 + (l&31), k-half = l>>5.
// W slices live in registers; h double-buffered in LDS (1 barrier/step).
// Per step, each wave reduces w_eff[j]*h[j] over its 32 outputs and lane 0
// writes one float to partbuf[(dir*64+b)*4 + w][t].
// ---------------------------------------------------------------------------
__global__ __launch_bounds__(256, 1)
void brnn_recur(const float* __restrict__ x,
                const float* __restrict__ Wih_f, const float* __restrict__ Whh_f,
                const float* __restrict__ bih_f, const float* __restrict__ bhh_f,
                const float* __restrict__ Wih_b, const float* __restrict__ Whh_b,
                const float* __restrict__ bih_b, const float* __restrict__ bhh_b,
                const float* __restrict__ weff,  float* __restrict__ partbuf)
{
    const int blk  = blockIdx.x;
    const int dir  = blk >> 6;      // 0 = forward, 1 = backward
    const int b    = blk & 63;
    const int tid  = threadIdx.x;
    const int w    = tid >> 6;
    const int l    = tid & 63;
    const int j    = w * 32 + (l & 31);
    const int half = l >> 5;

    const float* Wih = dir ? Wih_b : Wih_f;
    const float* Whh = dir ? Whh_b : Whh_f;
    const float* bih = dir ? bih_b : bih_f;
    const float* bhh = dir ? bhh_b : bhh_f;

    // Per-thread weight slices in registers.
    float whh[64];
    #pragma unroll
    for (int i = 0; i < 16; ++i)
        ((float4*)whh)[i] = ((const float4*)(Whh + j * 128 + half * 64))[i];
    float wih[32];
    #pragma unroll
    for (int i = 0; i < 8; ++i)
        ((float4*)wih)[i] = ((const float4*)(Wih + j * 64 + half * 32))[i];

    const float btot = (half == 0) ? (bih[j] + bhh[j]) : 0.0f;
    const float wj   = weff[dir * 128 + j];

    __shared__ __align__(16) float hbuf[2][128];
    if (tid < 128) hbuf[0][tid] = 0.0f;
    __syncthreads();

    const float* xbase = x + (size_t)b * T_LEN * D_IN + half * 32;
    float* pout = partbuf + ((size_t)blk * 4 + w) * T_LEN;

    float4 xc[8], xn[8];
    {   // preload x for step 0
        const float4* xp = (const float4*)(xbase + (size_t)(dir ? (T_LEN - 1) : 0) * D_IN);
        #pragma unroll
        for (int i = 0; i < 8; ++i) xc[i] = xp[i];
    }

#define STEP(S, RD, XCUR, XNXT) do {                                           \
        const int s_  = (S);                                                   \
        const int sn_ = (s_ + 1 < T_LEN) ? (s_ + 1) : s_;                      \
        const int tn_ = dir ? (T_LEN - 1 - sn_) : sn_;                         \
        /* prefetch x for next step (broadcast, latency hidden by compute) */  \
        const float4* xp_ = (const float4*)(xbase + (size_t)tn_ * D_IN);       \
        _Pragma("unroll") for (int i = 0; i < 8; ++i) XNXT[i] = xp_[i];        \
        float acc = btot;                                                      \
        const float4* hv4_ = (const float4*)&hbuf[RD][half * 64];              \
        _Pragma("unroll") for (int i = 0; i < 16; ++i) {                       \
            float4 hv = hv4_[i];                                               \
            acc = fmaf(whh[4*i+0], hv.x, acc);                                 \
            acc = fmaf(whh[4*i+1], hv.y, acc);                                 \
            acc = fmaf(whh[4*i+2], hv.z, acc);                                 \
            acc = fmaf(whh[4*i+3], hv.w, acc);                                 \
        }                                                                      \
        _Pragma("unroll") for (int i = 0; i < 8; ++i) {                        \
            acc = fmaf(wih[4*i+0], XCUR[i].x, acc);                            \
            acc = fmaf(wih[4*i+1], XCUR[i].y, acc);                            \
            acc = fmaf(wih[4*i+2], XCUR[i].z, acc);                            \
            acc = fmaf(wih[4*i+3], XCUR[i].w, acc);                            \
        }                                                                      \
        float h_ = acc + __shfl_xor(acc, 32);                                  \
        h_ = fmaxf(h_, 0.0f);                                                  \
        if (l < 32) hbuf[(RD) ^ 1][j] = h_;                                    \
        float p_ = h_ * wj;                                                    \
        p_ += __shfl_xor(p_, 1);                                               \
        p_ += __shfl_xor(p_, 2);                                               \
        p_ += __shfl_xor(p_, 4);                                               \
        p_ += __shfl_xor(p_, 8);                                               \
        p_ += __shfl_xor(p_, 16);                                              \
        const int t_ = dir ? (T_LEN - 1 - s_) : s_;                            \
        if (l == 0) pout[t_] = p_;                                             \
        __syncthreads();                                                       \
    } while (0)

    #pragma unroll 1
    for (int s = 0; s < T_LEN; s += 2) {
        STEP(s,     0, xc, xn);
        STEP(s + 1, 1, xn, xc);
    }
#undef STEP
}

// ---------------------------------------------------------------------------
// Kernel 3: assemble logits from partials and log-softmax over T per batch.
// One block per batch.
// ---------------------------------------------------------------------------
__global__ __launch_bounds__(256)
void brnn_lsm(const float* __restrict__ partbuf, const float* __restrict__ ws,
              float* __restrict__ out)
{
    const int b   = blockIdx.x;
    const int tid = threadIdx.x;
    __shared__ float lg[T_LEN];
    __shared__ float red[8];

    const float beff = ws[256];

    float lmax = -3.0e38f;
    for (int t = tid; t < T_LEN; t += 256) {
        float s = beff;
        #pragma unroll
        for (int dw = 0; dw < 8; ++dw) {
            const int dir = dw >> 2, wv = dw & 3;
            s += partbuf[(((size_t)(dir * 64 + b)) * 4 + wv) * T_LEN + t];
        }
        lg[t] = s;
        lmax = fmaxf(lmax, s);
    }
    #pragma unroll
    for (int m = 1; m <= 32; m <<= 1) lmax = fmaxf(lmax, __shfl_xor(lmax, m));
    if ((tid & 63) == 0) red[tid >> 6] = lmax;
    __syncthreads();
    const float bmax = fmaxf(fmaxf(red[0], red[1]), fmaxf(red[2], red[3]));

    float lsum = 0.0f;
    for (int t = tid; t < T_LEN; t += 256) lsum += expf(lg[t] - bmax);
    #pragma unroll
    for (int m = 1; m <= 32; m <<= 1) lsum += __shfl_xor(lsum, m);
    if ((tid & 63) == 0) red[4 + (tid >> 6)] = lsum;
    __syncthreads();
    const float lse = bmax + logf(red[4] + red[5] + red[6] + red[7]);

    for (int t = tid; t < T_LEN; t += 256)
        out[(size_t)b * T_LEN + t] = lg[t] - lse;
}

// ---------------------------------------------------------------------------
extern "C" void kernel_launch(void* const* d_in, const int* in_sizes, int n_in,
                              void* d_out, int out_size, void* d_ws, size_t ws_size,
                              hipStream_t stream)
{
    const float* x     = (const float*)d_in[0];
    const float* Wih_f = (const float*)d_in[1];
    const float* Whh_f = (const float*)d_in[2];
    const float* bih_f = (const float*)d_in[3];
    const float* bhh_f = (const float*)d_in[4];
    const float* Wih_b = (const float*)d_in[5];
    const float* Whh_b = (const float*)d_in[6];
    const float* bih_b = (const float*)d_in[7];
    const float* bhh_b = (const float*)d_in[8];
    const float* fc1_W = (const float*)d_in[9];
    const float* fc1_b = (const float*)d_in[10];
    const float* fc2_W = (const float*)d_in[11];
    const float* fc2_b = (const float*)d_in[12];
    float* out = (float*)d_out;

    float* wsf  = (float*)d_ws;
    float* part = wsf + 512;  // 2*64*4*2048 floats = 4 MB

    hipLaunchKernelGGL(prep_kernel, dim3(1), dim3(256), 0, stream,
                       fc1_W, fc1_b, fc2_W, fc2_b, wsf);
    hipLaunchKernelGGL(brnn_recur, dim3(128), dim3(256), 0, stream,
                       x, Wih_f, Whh_f, bih_f, bhh_f,
                       Wih_b, Whh_b, bih_b, bhh_b, wsf, part);
    hipLaunchKernelGGL(brnn_lsm, dim3(64), dim3(256), 0, stream,
                       part, wsf, out);
}

// Round 2
// 1229.503 us; speedup vs baseline: 1.0920x; 1.0920x over previous
//
#include <hip/hip_runtime.h>
#include <hip/hip_bf16.h>

#define T_LEN 2048
#define B_SZ  64
#define D_IN  64
#define H_SZ  128

// ---------------------------------------------------------------------------
// Kernel 1: collapse fc1+fc2 (no nonlinearity between them) into
//   w_eff[i] = sum_o fc2_W[o] * fc1_W[o, i]   (i in [0,256))
//   b_eff    = sum_o fc2_W[o] * fc1_b[o] + fc2_b
// ws layout (floats): [0..255]=w_eff, [256]=b_eff, [512..]=partials
// ---------------------------------------------------------------------------
__global__ __launch_bounds__(256)
void prep_kernel(const float* __restrict__ fc1_W, const float* __restrict__ fc1_b,
                 const float* __restrict__ fc2_W, const float* __restrict__ fc2_b,
                 float* __restrict__ ws)
{
    const int i = threadIdx.x;  // 0..255
    float s = 0.0f;
    #pragma unroll 4
    for (int o = 0; o < 128; ++o) s = fmaf(fc2_W[o], fc1_W[o * 256 + i], s);
    ws[i] = s;

    __shared__ float red[128];
    if (i < 128) red[i] = fc2_W[i] * fc1_b[i];
    __syncthreads();
    if (i == 0) {
        float b = fc2_b[0];
        for (int o = 0; o < 128; ++o) b += red[o];
        ws[256] = b;
    }
}

// DPP-based full-wave (64-lane) sum: result lands in lane 63.
// row_shr:1/2/4/8 then bcast15 (lane15->row1, lane47->row3) then bcast31
// (lane31->rows 2,3). bound_ctrl=true: invalid-source lanes contribute 0.
#define DPP_ADD_F32(v, ctrl)                                                   \
    v += __int_as_float(__builtin_amdgcn_update_dpp(                           \
            0, __float_as_int(v), (ctrl), 0xf, 0xf, true))

// ---------------------------------------------------------------------------
// Kernel 2: fused input-projection + ReLU recurrence + logit partial dot.
// One block per (dir, batch) chain: 128 blocks, 256 threads, 1 wave/SIMD.
// Thread (w = tid>>6, l = tid&63): output j = w*32 + (l&31), k-half = l>>5.
// W slices in registers; h double-buffered in LDS (1 barrier/step).
// Latency engineering: 8 accumulators (FMA chain ~12 deep), DPP p-reduce
// (VALU, ~24cy vs ~500cy for 5 dependent shuffles), and the global p-store
// deferred one step so its vmcnt drain hides under the next step's compute.
// ---------------------------------------------------------------------------
__global__ __launch_bounds__(256, 1)
void brnn_recur(const float* __restrict__ x,
                const float* __restrict__ Wih_f, const float* __restrict__ Whh_f,
                const float* __restrict__ bih_f, const float* __restrict__ bhh_f,
                const float* __restrict__ Wih_b, const float* __restrict__ Whh_b,
                const float* __restrict__ bih_b, const float* __restrict__ bhh_b,
                const float* __restrict__ weff,  float* __restrict__ partbuf)
{
    const int blk  = blockIdx.x;
    const int dir  = blk >> 6;      // 0 = forward, 1 = backward
    const int b    = blk & 63;
    const int tid  = threadIdx.x;
    const int w    = tid >> 6;
    const int l    = tid & 63;
    const int j    = w * 32 + (l & 31);
    const int half = l >> 5;

    const float* Wih = dir ? Wih_b : Wih_f;
    const float* Whh = dir ? Whh_b : Whh_f;
    const float* bih = dir ? bih_b : bih_f;
    const float* bhh = dir ? bhh_b : bhh_f;

    // Per-thread weight slices in registers.
    float whh[64];
    #pragma unroll
    for (int i = 0; i < 16; ++i)
        ((float4*)whh)[i] = ((const float4*)(Whh + j * 128 + half * 64))[i];
    float wih[32];
    #pragma unroll
    for (int i = 0; i < 8; ++i)
        ((float4*)wih)[i] = ((const float4*)(Wih + j * 64 + half * 32))[i];

    const float btot = (half == 0) ? (bih[j] + bhh[j]) : 0.0f;
    const float wj   = weff[dir * 128 + j];

    __shared__ __align__(16) float hbuf[2][128];
    if (tid < 128) hbuf[0][tid] = 0.0f;
    __syncthreads();

    const float* xbase = x + (size_t)b * T_LEN * D_IN + half * 32;
    float* pout = partbuf + ((size_t)blk * 4 + w) * T_LEN;

    float4 xc[8], xn[8];
    {   // preload x for step 0
        const float4* xp = (const float4*)(xbase + (size_t)(dir ? (T_LEN - 1) : 0) * D_IN);
        #pragma unroll
        for (int i = 0; i < 8; ++i) xc[i] = xp[i];
    }

    float p_prev = 0.0f;
    int   t_prev = 0;

#define STEP(S, RD, XCUR, XNXT) do {                                           \
        const int s_  = (S);                                                   \
        const int sn_ = (s_ + 1 < T_LEN) ? (s_ + 1) : s_;                      \
        const int tn_ = dir ? (T_LEN - 1 - sn_) : sn_;                         \
        /* deferred store of previous step's partial (drains off-path) */      \
        if (s_ > 0 && l == 63) pout[t_prev] = p_prev;                          \
        /* prefetch x for next step (broadcast, hidden under compute) */       \
        const float4* xp_ = (const float4*)(xbase + (size_t)tn_ * D_IN);       \
        _Pragma("unroll") for (int i = 0; i < 8; ++i) XNXT[i] = xp_[i];        \
        /* issue h reads early */                                              \
        const float4* hv4_ = (const float4*)&hbuf[RD][half * 64];              \
        float4 hr_[16];                                                        \
        _Pragma("unroll") for (int i = 0; i < 16; ++i) hr_[i] = hv4_[i];       \
        /* 8 independent accumulator chains */                                 \
        float a_[8];                                                           \
        a_[0] = btot;                                                          \
        _Pragma("unroll") for (int i = 1; i < 8; ++i) a_[i] = 0.0f;            \
        _Pragma("unroll") for (int i = 0; i < 8; ++i) {                        \
            a_[i] = fmaf(wih[4*i+0], XCUR[i].x, a_[i]);                        \
            a_[i] = fmaf(wih[4*i+1], XCUR[i].y, a_[i]);                        \
            a_[i] = fmaf(wih[4*i+2], XCUR[i].z, a_[i]);                        \
            a_[i] = fmaf(wih[4*i+3], XCUR[i].w, a_[i]);                        \
        }                                                                      \
        _Pragma("unroll") for (int i = 0; i < 16; ++i) {                       \
            a_[i & 7] = fmaf(whh[4*i+0], hr_[i].x, a_[i & 7]);                 \
            a_[i & 7] = fmaf(whh[4*i+1], hr_[i].y, a_[i & 7]);                 \
            a_[i & 7] = fmaf(whh[4*i+2], hr_[i].z, a_[i & 7]);                 \
            a_[i & 7] = fmaf(whh[4*i+3], hr_[i].w, a_[i & 7]);                 \
        }                                                                      \
        float acc = ((a_[0] + a_[1]) + (a_[2] + a_[3]))                        \
                  + ((a_[4] + a_[5]) + (a_[6] + a_[7]));                       \
        float h_ = acc + __shfl_xor(acc, 32);                                  \
        h_ = fmaxf(h_, 0.0f);                                                  \
        if (l < 32) hbuf[(RD) ^ 1][j] = h_;                                    \
        /* p-reduce across the wave via DPP (VALU-only, ~24cy).        */      \
        /* halves duplicate p, so 64-lane sum = 2x -> scale by 0.5.    */      \
        float p_ = h_ * wj;                                                    \
        DPP_ADD_F32(p_, 0x111);  /* row_shr:1 */                               \
        DPP_ADD_F32(p_, 0x112);  /* row_shr:2 */                               \
        DPP_ADD_F32(p_, 0x114);  /* row_shr:4 */                               \
        DPP_ADD_F32(p_, 0x118);  /* row_shr:8 */                               \
        DPP_ADD_F32(p_, 0x142);  /* row_bcast:15 */                            \
        DPP_ADD_F32(p_, 0x143);  /* row_bcast:31 */                            \
        p_prev = 0.5f * p_;                                                    \
        t_prev = dir ? (T_LEN - 1 - s_) : s_;                                  \
        __syncthreads();                                                       \
    } while (0)

    #pragma unroll 1
    for (int s = 0; s < T_LEN; s += 2) {
        STEP(s,     0, xc, xn);
        STEP(s + 1, 1, xn, xc);
    }
#undef STEP

    if (l == 63) pout[t_prev] = p_prev;  // last step's partial
}

// ---------------------------------------------------------------------------
// Kernel 3: assemble logits from partials and log-softmax over T per batch.
// One block per batch.
// ---------------------------------------------------------------------------
__global__ __launch_bounds__(256)
void brnn_lsm(const float* __restrict__ partbuf, const float* __restrict__ ws,
              float* __restrict__ out)
{
    const int b   = blockIdx.x;
    const int tid = threadIdx.x;
    __shared__ float lg[T_LEN];
    __shared__ float red[8];

    const float beff = ws[256];

    float lmax = -3.0e38f;
    for (int t = tid; t < T_LEN; t += 256) {
        float s = beff;
        #pragma unroll
        for (int dw = 0; dw < 8; ++dw) {
            const int dir = dw >> 2, wv = dw & 3;
            s += partbuf[(((size_t)(dir * 64 + b)) * 4 + wv) * T_LEN + t];
        }
        lg[t] = s;
        lmax = fmaxf(lmax, s);
    }
    #pragma unroll
    for (int m = 1; m <= 32; m <<= 1) lmax = fmaxf(lmax, __shfl_xor(lmax, m));
    if ((tid & 63) == 0) red[tid >> 6] = lmax;
    __syncthreads();
    const float bmax = fmaxf(fmaxf(red[0], red[1]), fmaxf(red[2], red[3]));

    float lsum = 0.0f;
    for (int t = tid; t < T_LEN; t += 256) lsum += expf(lg[t] - bmax);
    #pragma unroll
    for (int m = 1; m <= 32; m <<= 1) lsum += __shfl_xor(lsum, m);
    if ((tid & 63) == 0) red[4 + (tid >> 6)] = lsum;
    __syncthreads();
    const float lse = bmax + logf(red[4] + red[5] + red[6] + red[7]);

    for (int t = tid; t < T_LEN; t += 256)
        out[(size_t)b * T_LEN + t] = lg[t] - lse;
}

// ---------------------------------------------------------------------------
extern "C" void kernel_launch(void* const* d_in, const int* in_sizes, int n_in,
                              void* d_out, int out_size, void* d_ws, size_t ws_size,
                              hipStream_t stream)
{
    const float* x     = (const float*)d_in[0];
    const float* Wih_f = (const float*)d_in[1];
    const float* Whh_f = (const float*)d_in[2];
    const float* bih_f = (const float*)d_in[3];
    const float* bhh_f = (const float*)d_in[4];
    const float* Wih_b = (const float*)d_in[5];
    const float* Whh_b = (const float*)d_in[6];
    const float* bih_b = (const float*)d_in[7];
    const float* bhh_b = (const float*)d_in[8];
    const float* fc1_W = (const float*)d_in[9];
    const float* fc1_b = (const float*)d_in[10];
    const float* fc2_W = (const float*)d_in[11];
    const float* fc2_b = (const float*)d_in[12];
    float* out = (float*)d_out;

    float* wsf  = (float*)d_ws;
    float* part = wsf + 512;  // 2*64*4*2048 floats = 4 MB

    hipLaunchKernelGGL(prep_kernel, dim3(1), dim3(256), 0, stream,
                       fc1_W, fc1_b, fc2_W, fc2_b, wsf);
    hipLaunchKernelGGL(brnn_recur, dim3(128), dim3(256), 0, stream,
                       x, Wih_f, Whh_f, bih_f, bhh_f,
                       Wih_b, Whh_b, bih_b, bhh_b, wsf, part);
    hipLaunchKernelGGL(brnn_lsm, dim3(64), dim3(256), 0, stream,
                       part, wsf, out);
}

// Round 3
// 1074.841 us; speedup vs baseline: 1.2492x; 1.1439x over previous
//
#include <hip/hip_runtime.h>
#include <hip/hip_bf16.h>

#define T_LEN 2048
#define B_SZ  64
#define D_IN  64
#define H_SZ  128

// ---------------------------------------------------------------------------
// Kernel 1: collapse fc1+fc2 (no nonlinearity between them) into
//   w_eff[i] = sum_o fc2_W[o] * fc1_W[o, i]   (i in [0,256))
//   b_eff    = sum_o fc2_W[o] * fc1_b[o] + fc2_b
// ws layout (floats): [0..255]=w_eff, [256]=b_eff, [512..]=partials
// ---------------------------------------------------------------------------
__global__ __launch_bounds__(256)
void prep_kernel(const float* __restrict__ fc1_W, const float* __restrict__ fc1_b,
                 const float* __restrict__ fc2_W, const float* __restrict__ fc2_b,
                 float* __restrict__ ws)
{
    const int i = threadIdx.x;  // 0..255
    float s = 0.0f;
    #pragma unroll 4
    for (int o = 0; o < 128; ++o) s = fmaf(fc2_W[o], fc1_W[o * 256 + i], s);
    ws[i] = s;

    __shared__ float red[128];
    if (i < 128) red[i] = fc2_W[i] * fc1_b[i];
    __syncthreads();
    if (i == 0) {
        float b = fc2_b[0];
        for (int o = 0; o < 128; ++o) b += red[o];
        ws[256] = b;
    }
}

// DPP add: v += dpp_moved(v); bound_ctrl=true -> invalid source lanes give 0.
#define DPP_ADD_F32(v, ctrl)                                                   \
    v += __int_as_float(__builtin_amdgcn_update_dpp(                           \
            0, __float_as_int(v), (ctrl), 0xf, 0xf, true))

// h LDS layout: float k stored at index k + 4*(k>>4)  (80B row stride).
// Group g (k = g*16..g*16+15) is 16 contiguous floats at index 20*g, whose
// bank start 20g mod 32 = {0,20,8,28,16,4,24,12} -> conflict-free b128 reads.

// ---------------------------------------------------------------------------
// Kernel 2: fused input-projection + ReLU recurrence + logit partial dot.
// One block per (dir, batch) chain: 128 blocks, 256 threads, 1 wave/SIMD.
// Tiling: thread (wave w, lane l): m = l>>3 selects 4 outputs j0=w*32+4m,
// g = l&7 selects k-slice (h cols g*16..+15, x cols g*8..+7).
// Per-thread LDS h-read is 16 floats (was 64) -> 4x less LDS pipe pressure.
// k-partials reduced over each aligned 8-lane group via DPP row_shr chain
// (result lands in lane 8m+7, the writer lane).
// ---------------------------------------------------------------------------
__global__ __launch_bounds__(256, 1)
void brnn_recur(const float* __restrict__ x,
                const float* __restrict__ Wih_f, const float* __restrict__ Whh_f,
                const float* __restrict__ bih_f, const float* __restrict__ bhh_f,
                const float* __restrict__ Wih_b, const float* __restrict__ Whh_b,
                const float* __restrict__ bih_b, const float* __restrict__ bhh_b,
                const float* __restrict__ weff,  float* __restrict__ partbuf)
{
    const int blk  = blockIdx.x;
    const int dir  = blk >> 6;      // 0 = forward, 1 = backward
    const int b    = blk & 63;
    const int tid  = threadIdx.x;
    const int w    = tid >> 6;      // wave 0..3
    const int l    = tid & 63;      // lane
    const int g    = l & 7;         // k-group
    const int m    = l >> 3;        // j-subgroup 0..7
    const int j0   = w * 32 + m * 4;
    const bool wr  = (g == 7);      // writer lane of its 8-lane group

    const float* Wih = dir ? Wih_b : Wih_f;
    const float* Whh = dir ? Whh_b : Whh_f;
    const float* bih = dir ? bih_b : bih_f;
    const float* bhh = dir ? bhh_b : bhh_f;

    // Per-thread weight slices in registers: Whh rows j0..j0+3, cols g*16..+15.
    float whh[64];
    #pragma unroll
    for (int jj = 0; jj < 4; ++jj)
        #pragma unroll
        for (int i = 0; i < 4; ++i)
            ((float4*)whh)[jj * 4 + i] =
                *(const float4*)(Whh + (j0 + jj) * 128 + g * 16 + i * 4);
    // Wih rows j0..j0+3, cols g*8..+7.
    float wih[32];
    #pragma unroll
    for (int jj = 0; jj < 4; ++jj)
        #pragma unroll
        for (int i = 0; i < 2; ++i)
            ((float4*)wih)[jj * 2 + i] =
                *(const float4*)(Wih + (j0 + jj) * 64 + g * 8 + i * 4);

    // Bias enters once per output: via the g==0 lane of each group.
    float4 b4 = make_float4(0.f, 0.f, 0.f, 0.f);
    if (g == 0) {
        float4 bi = *(const float4*)(bih + j0);
        float4 bh = *(const float4*)(bhh + j0);
        b4 = make_float4(bi.x + bh.x, bi.y + bh.y, bi.z + bh.z, bi.w + bh.w);
    }
    const float4 w4 = *(const float4*)(weff + dir * 128 + j0);

    __shared__ __align__(16) float hbuf[2][160];  // padded layout, see above
    if (tid < 160) hbuf[0][tid] = 0.0f;
    __syncthreads();

    const float* xbase = x + (size_t)b * T_LEN * D_IN + g * 8;
    float* pout = partbuf + ((size_t)blk * 4 + w) * T_LEN;

    float xc[8], xn[8];
    {   // preload x for step 0
        const float4* xp = (const float4*)(xbase + (size_t)(dir ? (T_LEN - 1) : 0) * D_IN);
        ((float4*)xc)[0] = xp[0];
        ((float4*)xc)[1] = xp[1];
    }

    float p_prev = 0.0f;
    int   t_prev = 0;

    // writer's h store index: j0 + 4*(j0>>4) = 40w + 4m + 4*(m>>2)
    const int hwidx = 40 * w + 4 * m + 4 * (m >> 2);

#define STEP(S, RD, XCUR, XNXT) do {                                           \
        const int s_  = (S);                                                   \
        const int sn_ = (s_ + 1 < T_LEN) ? (s_ + 1) : s_;                      \
        const int tn_ = dir ? (T_LEN - 1 - sn_) : sn_;                         \
        /* deferred store of previous step's partial (drains off-path) */      \
        if (s_ > 0 && l == 63) pout[t_prev] = p_prev;                          \
        /* prefetch x for next step */                                         \
        const float4* xp_ = (const float4*)(xbase + (size_t)tn_ * D_IN);       \
        ((float4*)XNXT)[0] = xp_[0];                                           \
        ((float4*)XNXT)[1] = xp_[1];                                           \
        /* issue h reads (4 x b128, conflict-free), then overlap x-FMAs */     \
        const float4* hp_ = (const float4*)&hbuf[RD][20 * g];                  \
        float4 hv_[4];                                                         \
        _Pragma("unroll") for (int i = 0; i < 4; ++i) hv_[i] = hp_[i];         \
        float a0 = b4.x, a1 = b4.y, a2 = b4.z, a3 = b4.w;                      \
        _Pragma("unroll") for (int i = 0; i < 8; ++i) {                        \
            a0 = fmaf(wih[0 * 8 + i], XCUR[i], a0);                            \
            a1 = fmaf(wih[1 * 8 + i], XCUR[i], a1);                            \
            a2 = fmaf(wih[2 * 8 + i], XCUR[i], a2);                            \
            a3 = fmaf(wih[3 * 8 + i], XCUR[i], a3);                            \
        }                                                                      \
        _Pragma("unroll") for (int i = 0; i < 4; ++i) {                        \
            const float* hq_ = (const float*)&hv_[i];                          \
            _Pragma("unroll") for (int c = 0; c < 4; ++c) {                    \
                a0 = fmaf(whh[0 * 16 + i * 4 + c], hq_[c], a0);                \
                a1 = fmaf(whh[1 * 16 + i * 4 + c], hq_[c], a1);                \
                a2 = fmaf(whh[2 * 16 + i * 4 + c], hq_[c], a2);                \
                a3 = fmaf(whh[3 * 16 + i * 4 + c], hq_[c], a3);                \
            }                                                                  \
        }                                                                      \
        /* sum over the 8-lane k-group: lane 8m+7 accumulates its group */     \
        DPP_ADD_F32(a0, 0x111); DPP_ADD_F32(a1, 0x111);                        \
        DPP_ADD_F32(a2, 0x111); DPP_ADD_F32(a3, 0x111);                        \
        DPP_ADD_F32(a0, 0x112); DPP_ADD_F32(a1, 0x112);                        \
        DPP_ADD_F32(a2, 0x112); DPP_ADD_F32(a3, 0x112);                        \
        DPP_ADD_F32(a0, 0x114); DPP_ADD_F32(a1, 0x114);                        \
        DPP_ADD_F32(a2, 0x114); DPP_ADD_F32(a3, 0x114);                        \
        float4 h4_;                                                            \
        h4_.x = fmaxf(a0, 0.0f); h4_.y = fmaxf(a1, 0.0f);                      \
        h4_.z = fmaxf(a2, 0.0f); h4_.w = fmaxf(a3, 0.0f);                      \
        float p_ = 0.0f;                                                       \
        if (wr) {                                                              \
            *(float4*)&hbuf[(RD) ^ 1][hwidx] = h4_;                            \
            p_ = w4.x * h4_.x + w4.y * h4_.y + w4.z * h4_.z + w4.w * h4_.w;    \
        }                                                                      \
        /* full-wave sum of p via DPP; result lands in lane 63 */              \
        DPP_ADD_F32(p_, 0x111);                                                \
        DPP_ADD_F32(p_, 0x112);                                                \
        DPP_ADD_F32(p_, 0x114);                                                \
        DPP_ADD_F32(p_, 0x118);                                                \
        DPP_ADD_F32(p_, 0x142);  /* row_bcast:15 */                            \
        DPP_ADD_F32(p_, 0x143);  /* row_bcast:31 */                            \
        p_prev = p_;                                                           \
        t_prev = dir ? (T_LEN - 1 - s_) : s_;                                  \
        __syncthreads();                                                       \
    } while (0)

    #pragma unroll 1
    for (int s = 0; s < T_LEN; s += 2) {
        STEP(s,     0, xc, xn);
        STEP(s + 1, 1, xn, xc);
    }
#undef STEP

    if (l == 63) pout[t_prev] = p_prev;  // last step's partial
}

// ---------------------------------------------------------------------------
// Kernel 3: assemble logits from partials and log-softmax over T per batch.
// One block per batch.
// ---------------------------------------------------------------------------
__global__ __launch_bounds__(256)
void brnn_lsm(const float* __restrict__ partbuf, const float* __restrict__ ws,
              float* __restrict__ out)
{
    const int b   = blockIdx.x;
    const int tid = threadIdx.x;
    __shared__ float lg[T_LEN];
    __shared__ float red[8];

    const float beff = ws[256];

    float lmax = -3.0e38f;
    for (int t = tid; t < T_LEN; t += 256) {
        float s = beff;
        #pragma unroll
        for (int dw = 0; dw < 8; ++dw) {
            const int dir = dw >> 2, wv = dw & 3;
            s += partbuf[(((size_t)(dir * 64 + b)) * 4 + wv) * T_LEN + t];
        }
        lg[t] = s;
        lmax = fmaxf(lmax, s);
    }
    #pragma unroll
    for (int mm = 1; mm <= 32; mm <<= 1) lmax = fmaxf(lmax, __shfl_xor(lmax, mm));
    if ((tid & 63) == 0) red[tid >> 6] = lmax;
    __syncthreads();
    const float bmax = fmaxf(fmaxf(red[0], red[1]), fmaxf(red[2], red[3]));

    float lsum = 0.0f;
    for (int t = tid; t < T_LEN; t += 256) lsum += expf(lg[t] - bmax);
    #pragma unroll
    for (int mm = 1; mm <= 32; mm <<= 1) lsum += __shfl_xor(lsum, mm);
    if ((tid & 63) == 0) red[4 + (tid >> 6)] = lsum;
    __syncthreads();
    const float lse = bmax + logf(red[4] + red[5] + red[6] + red[7]);

    for (int t = tid; t < T_LEN; t += 256)
        out[(size_t)b * T_LEN + t] = lg[t] - lse;
}

// ---------------------------------------------------------------------------
extern "C" void kernel_launch(void* const* d_in, const int* in_sizes, int n_in,
                              void* d_out, int out_size, void* d_ws, size_t ws_size,
                              hipStream_t stream)
{
    const float* x     = (const float*)d_in[0];
    const float* Wih_f = (const float*)d_in[1];
    const float* Whh_f = (const float*)d_in[2];
    const float* bih_f = (const float*)d_in[3];
    const float* bhh_f = (const float*)d_in[4];
    const float* Wih_b = (const float*)d_in[5];
    const float* Whh_b = (const float*)d_in[6];
    const float* bih_b = (const float*)d_in[7];
    const float* bhh_b = (const float*)d_in[8];
    const float* fc1_W = (const float*)d_in[9];
    const float* fc1_b = (const float*)d_in[10];
    const float* fc2_W = (const float*)d_in[11];
    const float* fc2_b = (const float*)d_in[12];
    float* out = (float*)d_out;

    float* wsf  = (float*)d_ws;
    float* part = wsf + 512;  // 2*64*4*2048 floats = 4 MB

    hipLaunchKernelGGL(prep_kernel, dim3(1), dim3(256), 0, stream,
                       fc1_W, fc1_b, fc2_W, fc2_b, wsf);
    hipLaunchKernelGGL(brnn_recur, dim3(128), dim3(256), 0, stream,
                       x, Wih_f, Whh_f, bih_f, bhh_f,
                       Wih_b, Whh_b, bih_b, bhh_b, wsf, part);
    hipLaunchKernelGGL(brnn_lsm, dim3(64), dim3(256), 0, stream,
                       part, wsf, out);
}

// Round 4
// 800.647 us; speedup vs baseline: 1.6769x; 1.3425x over previous
//
#include <hip/hip_runtime.h>
#include <hip/hip_bf16.h>

#define T_LEN 2048
#define B_SZ  64
#define D_IN  64
#define H_SZ  128

// ---------------------------------------------------------------------------
// Kernel 1: collapse fc1+fc2 (no nonlinearity between them) into
//   w_eff[i] = sum_o fc2_W[o] * fc1_W[o, i]   (i in [0,256))
//   b_eff    = sum_o fc2_W[o] * fc1_b[o] + fc2_b
// ws layout (floats): [0..255]=w_eff, [256]=b_eff, [512..]=partials
// ---------------------------------------------------------------------------
__global__ __launch_bounds__(256)
void prep_kernel(const float* __restrict__ fc1_W, const float* __restrict__ fc1_b,
                 const float* __restrict__ fc2_W, const float* __restrict__ fc2_b,
                 float* __restrict__ ws)
{
    const int i = threadIdx.x;  // 0..255
    float s = 0.0f;
    #pragma unroll 4
    for (int o = 0; o < 128; ++o) s = fmaf(fc2_W[o], fc1_W[o * 256 + i], s);
    ws[i] = s;

    __shared__ float red[128];
    if (i < 128) red[i] = fc2_W[i] * fc1_b[i];
    __syncthreads();
    if (i == 0) {
        float b = fc2_b[0];
        for (int o = 0; o < 128; ++o) b += red[o];
        ws[256] = b;
    }
}

// DPP add: v += dpp_moved(v); bound_ctrl=true -> invalid source lanes give 0.
#define DPP_ADD_F32(v, ctrl)                                                   \
    v += __int_as_float(__builtin_amdgcn_update_dpp(                           \
            0, __float_as_int(v), (ctrl), 0xf, 0xf, true))

// Hand-rolled barrier: lgkmcnt(0) (ds_write visibility) WITHOUT the vmcnt(0)
// drain __syncthreads() emits. Global x-prefetch loads / p stores float
// across it with counted vmcnt waits. sched_barrier(0) pins LDS ops to
// their step (compiler may otherwise move memory ops across s_barrier).
__device__ __forceinline__ void chain_barrier() {
    asm volatile("s_waitcnt lgkmcnt(0)" ::: "memory");
    __builtin_amdgcn_s_barrier();
    __builtin_amdgcn_sched_barrier(0);
}

// h LDS layout: float k stored at index k + 4*(k>>4)  (80B row stride).
// Group g (k = g*16..g*16+15) is 16 contiguous floats at index 20*g, whose
// bank start 20g mod 32 = {0,20,8,28,16,4,24,12} -> conflict-free b128 reads.

// ---------------------------------------------------------------------------
// Kernel 2: fused input-projection + ReLU recurrence + logit partial dot.
// One block per (dir, batch) chain: 128 blocks, 256 threads, 1 wave/SIMD.
// Tiling: thread (wave w, lane l): m = l>>3 selects 4 outputs j0=w*32+4m,
// g = l&7 selects k-slice (h cols g*16..+15, x cols g*8..+7).
// k-partials reduced over each aligned 8-lane group via DPP row_shr chain
// (result lands in lane 8m+7, the writer lane).
// Latency engineering: custom barrier (no vmcnt drain), x prefetch distance
// 2 (4 rotating buffers), p-reduce deferred one step to hide under ds_read.
// ---------------------------------------------------------------------------
__global__ __launch_bounds__(256, 1)
void brnn_recur(const float* __restrict__ x,
                const float* __restrict__ Wih_f, const float* __restrict__ Whh_f,
                const float* __restrict__ bih_f, const float* __restrict__ bhh_f,
                const float* __restrict__ Wih_b, const float* __restrict__ Whh_b,
                const float* __restrict__ bih_b, const float* __restrict__ bhh_b,
                const float* __restrict__ weff,  float* __restrict__ partbuf)
{
    const int blk  = blockIdx.x;
    const int dir  = blk >> 6;      // 0 = forward, 1 = backward
    const int b    = blk & 63;
    const int tid  = threadIdx.x;
    const int w    = tid >> 6;      // wave 0..3
    const int l    = tid & 63;      // lane
    const int g    = l & 7;         // k-group
    const int m    = l >> 3;        // j-subgroup 0..7
    const int j0   = w * 32 + m * 4;
    const bool wr  = (g == 7);      // writer lane of its 8-lane group

    const float* Wih = dir ? Wih_b : Wih_f;
    const float* Whh = dir ? Whh_b : Whh_f;
    const float* bih = dir ? bih_b : bih_f;
    const float* bhh = dir ? bhh_b : bhh_f;

    // Per-thread weight slices in registers: Whh rows j0..j0+3, cols g*16..+15.
    float whh[64];
    #pragma unroll
    for (int jj = 0; jj < 4; ++jj)
        #pragma unroll
        for (int i = 0; i < 4; ++i)
            ((float4*)whh)[jj * 4 + i] =
                *(const float4*)(Whh + (j0 + jj) * 128 + g * 16 + i * 4);
    // Wih rows j0..j0+3, cols g*8..+7.
    float wih[32];
    #pragma unroll
    for (int jj = 0; jj < 4; ++jj)
        #pragma unroll
        for (int i = 0; i < 2; ++i)
            ((float4*)wih)[jj * 2 + i] =
                *(const float4*)(Wih + (j0 + jj) * 64 + g * 8 + i * 4);

    // Bias enters once per output: via the g==0 lane of each group.
    float4 b4 = make_float4(0.f, 0.f, 0.f, 0.f);
    if (g == 0) {
        float4 bi = *(const float4*)(bih + j0);
        float4 bh = *(const float4*)(bhh + j0);
        b4 = make_float4(bi.x + bh.x, bi.y + bh.y, bi.z + bh.z, bi.w + bh.w);
    }
    const float4 w4 = *(const float4*)(weff + dir * 128 + j0);

    __shared__ __align__(16) float hbuf[2][160];  // padded layout, see above
    if (tid < 160) hbuf[0][tid] = 0.0f;
    __syncthreads();

    const float* xbase = x + (size_t)b * T_LEN * D_IN + g * 8;
    float* pout = partbuf + ((size_t)blk * 4 + w) * T_LEN;

    // 4 rotating x buffers: xq0..xq3 hold steps s with s&3 == 0..3.
    float xq0[8], xq1[8], xq2[8], xq3[8];
    {   // preload x for steps 0 and 1
        const float4* xp0 = (const float4*)(xbase + (size_t)(dir ? (T_LEN - 1) : 0) * D_IN);
        ((float4*)xq0)[0] = xp0[0];
        ((float4*)xq0)[1] = xp0[1];
        const float4* xp1 = (const float4*)(xbase + (size_t)(dir ? (T_LEN - 2) : 1) * D_IN);
        ((float4*)xq1)[0] = xp1[0];
        ((float4*)xq1)[1] = xp1[1];
    }

    float p_carry = 0.0f;   // per-lane p contribution of previous step
    int   t_prev  = 0;

    // writer's h store index: j0 + 4*(j0>>4) = 40w + 4m + 4*(m>>2)
    const int hwidx = 40 * w + 4 * m + 4 * (m >> 2);

#define STEP(S, RD, XCUR, XPRE) do {                                           \
        const int s_  = (S);                                                   \
        /* finish previous step's p: DPP reduce + store. Runs right after */   \
        /* the barrier, hiding under this step's ds_read latency.         */   \
        if (s_ > 0) {                                                          \
            float pr_ = p_carry;                                               \
            DPP_ADD_F32(pr_, 0x111); DPP_ADD_F32(pr_, 0x112);                  \
            DPP_ADD_F32(pr_, 0x114); DPP_ADD_F32(pr_, 0x118);                  \
            DPP_ADD_F32(pr_, 0x142); DPP_ADD_F32(pr_, 0x143);                  \
            if (l == 63) pout[t_prev] = pr_;                                   \
        }                                                                      \
        /* prefetch x for step s+2 (distance 2: covers HBM-miss latency) */    \
        {                                                                      \
            const int sp_ = (s_ + 2 < T_LEN) ? (s_ + 2) : (T_LEN - 1);         \
            const int tp_ = dir ? (T_LEN - 1 - sp_) : sp_;                     \
            const float4* xp_ = (const float4*)(xbase + (size_t)tp_ * D_IN);   \
            ((float4*)XPRE)[0] = xp_[0];                                       \
            ((float4*)XPRE)[1] = xp_[1];                                       \
        }                                                                      \
        /* h reads (4 x b128, conflict-free); x-FMAs overlap the latency */    \
        const float4* hp_ = (const float4*)&hbuf[RD][20 * g];                  \
        float4 hv_[4];                                                         \
        _Pragma("unroll") for (int i = 0; i < 4; ++i) hv_[i] = hp_[i];         \
        float a0 = b4.x, a1 = b4.y, a2 = b4.z, a3 = b4.w;                      \
        _Pragma("unroll") for (int i = 0; i < 8; ++i) {                        \
            a0 = fmaf(wih[0 * 8 + i], XCUR[i], a0);                            \
            a1 = fmaf(wih[1 * 8 + i], XCUR[i], a1);                            \
            a2 = fmaf(wih[2 * 8 + i], XCUR[i], a2);                            \
            a3 = fmaf(wih[3 * 8 + i], XCUR[i], a3);                            \
        }                                                                      \
        _Pragma("unroll") for (int i = 0; i < 4; ++i) {                        \
            const float* hq_ = (const float*)&hv_[i];                          \
            _Pragma("unroll") for (int c = 0; c < 4; ++c) {                    \
                a0 = fmaf(whh[0 * 16 + i * 4 + c], hq_[c], a0);                \
                a1 = fmaf(whh[1 * 16 + i * 4 + c], hq_[c], a1);                \
                a2 = fmaf(whh[2 * 16 + i * 4 + c], hq_[c], a2);                \
                a3 = fmaf(whh[3 * 16 + i * 4 + c], hq_[c], a3);                \
            }                                                                  \
        }                                                                      \
        /* sum over the 8-lane k-group: lane 8m+7 accumulates its group */     \
        DPP_ADD_F32(a0, 0x111); DPP_ADD_F32(a1, 0x111);                        \
        DPP_ADD_F32(a2, 0x111); DPP_ADD_F32(a3, 0x111);                        \
        DPP_ADD_F32(a0, 0x112); DPP_ADD_F32(a1, 0x112);                        \
        DPP_ADD_F32(a2, 0x112); DPP_ADD_F32(a3, 0x112);                        \
        DPP_ADD_F32(a0, 0x114); DPP_ADD_F32(a1, 0x114);                        \
        DPP_ADD_F32(a2, 0x114); DPP_ADD_F32(a3, 0x114);                        \
        float4 h4_;                                                            \
        h4_.x = fmaxf(a0, 0.0f); h4_.y = fmaxf(a1, 0.0f);                      \
        h4_.z = fmaxf(a2, 0.0f); h4_.w = fmaxf(a3, 0.0f);                      \
        p_carry = 0.0f;                                                        \
        if (wr) {                                                              \
            *(float4*)&hbuf[(RD) ^ 1][hwidx] = h4_;                            \
            p_carry = w4.x * h4_.x + w4.y * h4_.y                              \
                    + w4.z * h4_.z + w4.w * h4_.w;                             \
        }                                                                      \
        t_prev = dir ? (T_LEN - 1 - s_) : s_;                                  \
        chain_barrier();                                                       \
    } while (0)

    #pragma unroll 1
    for (int s = 0; s < T_LEN; s += 4) {
        STEP(s,     0, xq0, xq2);
        STEP(s + 1, 1, xq1, xq3);
        STEP(s + 2, 0, xq2, xq0);
        STEP(s + 3, 1, xq3, xq1);
    }
#undef STEP

    {   // last step's partial
        float pr = p_carry;
        DPP_ADD_F32(pr, 0x111); DPP_ADD_F32(pr, 0x112);
        DPP_ADD_F32(pr, 0x114); DPP_ADD_F32(pr, 0x118);
        DPP_ADD_F32(pr, 0x142); DPP_ADD_F32(pr, 0x143);
        if (l == 63) pout[t_prev] = pr;
    }
}

// ---------------------------------------------------------------------------
// Kernel 3: assemble logits from partials and log-softmax over T per batch.
// One block per batch.
// ---------------------------------------------------------------------------
__global__ __launch_bounds__(256)
void brnn_lsm(const float* __restrict__ partbuf, const float* __restrict__ ws,
              float* __restrict__ out)
{
    const int b   = blockIdx.x;
    const int tid = threadIdx.x;
    __shared__ float lg[T_LEN];
    __shared__ float red[8];

    const float beff = ws[256];

    float lmax = -3.0e38f;
    for (int t = tid; t < T_LEN; t += 256) {
        float s = beff;
        #pragma unroll
        for (int dw = 0; dw < 8; ++dw) {
            const int dir = dw >> 2, wv = dw & 3;
            s += partbuf[(((size_t)(dir * 64 + b)) * 4 + wv) * T_LEN + t];
        }
        lg[t] = s;
        lmax = fmaxf(lmax, s);
    }
    #pragma unroll
    for (int mm = 1; mm <= 32; mm <<= 1) lmax = fmaxf(lmax, __shfl_xor(lmax, mm));
    if ((tid & 63) == 0) red[tid >> 6] = lmax;
    __syncthreads();
    const float bmax = fmaxf(fmaxf(red[0], red[1]), fmaxf(red[2], red[3]));

    float lsum = 0.0f;
    for (int t = tid; t < T_LEN; t += 256) lsum += expf(lg[t] - bmax);
    #pragma unroll
    for (int mm = 1; mm <= 32; mm <<= 1) lsum += __shfl_xor(lsum, mm);
    if ((tid & 63) == 0) red[4 + (tid >> 6)] = lsum;
    __syncthreads();
    const float lse = bmax + logf(red[4] + red[5] + red[6] + red[7]);

    for (int t = tid; t < T_LEN; t += 256)
        out[(size_t)b * T_LEN + t] = lg[t] - lse;
}

// ---------------------------------------------------------------------------
extern "C" void kernel_launch(void* const* d_in, const int* in_sizes, int n_in,
                              void* d_out, int out_size, void* d_ws, size_t ws_size,
                              hipStream_t stream)
{
    const float* x     = (const float*)d_in[0];
    const float* Wih_f = (const float*)d_in[1];
    const float* Whh_f = (const float*)d_in[2];
    const float* bih_f = (const float*)d_in[3];
    const float* bhh_f = (const float*)d_in[4];
    const float* Wih_b = (const float*)d_in[5];
    const float* Whh_b = (const float*)d_in[6];
    const float* bih_b = (const float*)d_in[7];
    const float* bhh_b = (const float*)d_in[8];
    const float* fc1_W = (const float*)d_in[9];
    const float* fc1_b = (const float*)d_in[10];
    const float* fc2_W = (const float*)d_in[11];
    const float* fc2_b = (const float*)d_in[12];
    float* out = (float*)d_out;

    float* wsf  = (float*)d_ws;
    float* part = wsf + 512;  // 2*64*4*2048 floats = 4 MB

    hipLaunchKernelGGL(prep_kernel, dim3(1), dim3(256), 0, stream,
                       fc1_W, fc1_b, fc2_W, fc2_b, wsf);
    hipLaunchKernelGGL(brnn_recur, dim3(128), dim3(256), 0, stream,
                       x, Wih_f, Whh_f, bih_f, bhh_f,
                       Wih_b, Whh_b, bih_b, bhh_b, wsf, part);
    hipLaunchKernelGGL(brnn_lsm, dim3(64), dim3(256), 0, stream,
                       part, wsf, out);
}

// Round 5
// 800.471 us; speedup vs baseline: 1.6773x; 1.0002x over previous
//
#include <hip/hip_runtime.h>
#include <hip/hip_bf16.h>

#define T_LEN 2048
#define B_SZ  64
#define D_IN  64
#define H_SZ  128

// ---------------------------------------------------------------------------
// Kernel 1: collapse fc1+fc2 (no nonlinearity between them) into
//   w_eff[i] = sum_o fc2_W[o] * fc1_W[o, i]   (i in [0,256))
//   b_eff    = sum_o fc2_W[o] * fc1_b[o] + fc2_b
// ws layout (floats): [0..255]=w_eff, [256]=b_eff, [512..]=partials, then xp
// ---------------------------------------------------------------------------
__global__ __launch_bounds__(256)
void prep_kernel(const float* __restrict__ fc1_W, const float* __restrict__ fc1_b,
                 const float* __restrict__ fc2_W, const float* __restrict__ fc2_b,
                 float* __restrict__ ws)
{
    const int i = threadIdx.x;  // 0..255
    float s = 0.0f;
    #pragma unroll 4
    for (int o = 0; o < 128; ++o) s = fmaf(fc2_W[o], fc1_W[o * 256 + i], s);
    ws[i] = s;

    __shared__ float red[128];
    if (i < 128) red[i] = fc2_W[i] * fc1_b[i];
    __syncthreads();
    if (i == 0) {
        float b = fc2_b[0];
        for (int o = 0; o < 128; ++o) b += red[o];
        ws[256] = b;
    }
}

// ---------------------------------------------------------------------------
// Kernel 1b: xp[dir][b][t][j] = sum_d x[b][t][d]*Wih[j][d] + bih[j] + bhh[j]
// Hoists the input projection out of the sequential recurrence.
// Grid: 2048 blocks = dir(2) x b(64) x tchunk(16 of 128 rows); 128 threads,
// thread = output j. x rows staged in LDS (32KB), broadcast-read per t.
// ---------------------------------------------------------------------------
__global__ __launch_bounds__(128)
void xp_gemm(const float* __restrict__ x,
             const float* __restrict__ Wih_f, const float* __restrict__ bih_f,
             const float* __restrict__ bhh_f,
             const float* __restrict__ Wih_b, const float* __restrict__ bih_b,
             const float* __restrict__ bhh_b,
             float* __restrict__ xp)
{
    const int blk = blockIdx.x;
    const int dir = blk >> 10;
    const int b   = (blk >> 4) & 63;
    const int c   = blk & 15;          // t-chunk of 128
    const int j   = threadIdx.x;       // 0..127

    const float* Wih = dir ? Wih_b : Wih_f;
    const float* bih = dir ? bih_b : bih_f;
    const float* bhh = dir ? bhh_b : bhh_f;

    __shared__ __align__(16) float xs[128][64];   // 32 KB
    const float4* xsrc = (const float4*)(x + ((size_t)b * T_LEN + c * 128) * D_IN);
    float4* xdst = (float4*)&xs[0][0];
    #pragma unroll
    for (int i = 0; i < 16; ++i) xdst[threadIdx.x + i * 128] = xsrc[threadIdx.x + i * 128];

    float wr[64];
    #pragma unroll
    for (int i = 0; i < 16; ++i) ((float4*)wr)[i] = ((const float4*)(Wih + j * 64))[i];
    const float bj = bih[j] + bhh[j];
    __syncthreads();

    float* xpo = xp + (((size_t)(dir * 64 + b)) * T_LEN + c * 128) * H_SZ + j;
    for (int tt = 0; tt < 128; ++tt) {
        const float4* xr = (const float4*)&xs[tt][0];
        float a0 = bj, a1 = 0.f, a2 = 0.f, a3 = 0.f;
        #pragma unroll
        for (int i = 0; i < 16; i += 4) {
            float4 v0 = xr[i], v1 = xr[i + 1], v2 = xr[i + 2], v3 = xr[i + 3];
            a0 = fmaf(wr[4*i+ 0], v0.x, a0); a0 = fmaf(wr[4*i+ 1], v0.y, a0);
            a0 = fmaf(wr[4*i+ 2], v0.z, a0); a0 = fmaf(wr[4*i+ 3], v0.w, a0);
            a1 = fmaf(wr[4*i+ 4], v1.x, a1); a1 = fmaf(wr[4*i+ 5], v1.y, a1);
            a1 = fmaf(wr[4*i+ 6], v1.z, a1); a1 = fmaf(wr[4*i+ 7], v1.w, a1);
            a2 = fmaf(wr[4*i+ 8], v2.x, a2); a2 = fmaf(wr[4*i+ 9], v2.y, a2);
            a2 = fmaf(wr[4*i+10], v2.z, a2); a2 = fmaf(wr[4*i+11], v2.w, a2);
            a3 = fmaf(wr[4*i+12], v3.x, a3); a3 = fmaf(wr[4*i+13], v3.y, a3);
            a3 = fmaf(wr[4*i+14], v3.z, a3); a3 = fmaf(wr[4*i+15], v3.w, a3);
        }
        xpo[(size_t)tt * H_SZ] = (a0 + a1) + (a2 + a3);
    }
}

// DPP add: v += dpp_moved(v); bound_ctrl=true -> invalid source lanes give 0.
#define DPP_ADD_F32(v, ctrl)                                                   \
    v += __int_as_float(__builtin_amdgcn_update_dpp(                           \
            0, __float_as_int(v), (ctrl), 0xf, 0xf, true))

// Hand-rolled barrier: lgkmcnt(0) (ds visibility) WITHOUT the vmcnt(0) drain
// __syncthreads() emits; global loads/stores float across with counted waits.
__device__ __forceinline__ void chain_barrier() {
    asm volatile("s_waitcnt lgkmcnt(0)" ::: "memory");
    __builtin_amdgcn_s_barrier();
    __builtin_amdgcn_sched_barrier(0);
}

// h LDS layout: float k stored at index k + 4*(k>>4)  (80B row stride).
// Group g (k = g*16..g*16+15) is 16 contiguous floats at index 20*g ->
// bank starts {0,20,8,28,16,4,24,12} -> conflict-free b128 reads.

// ---------------------------------------------------------------------------
// Kernel 2 (xp version): pure ReLU recurrence + logit partial dot.
// One block per (dir, batch) chain: 128 blocks, 256 threads, 1 wave/SIMD.
// Thread (wave w, lane l): m = l>>3 -> 4 outputs j0=w*32+4m; g = l&7 ->
// k-slice (h cols g*16..+15). Step body: 4 ds_read -> 64 FMA -> 3 DPP ->
// ds_write. xp arrives as one prefetched dwordx4 (distance 2).
// Deferred p-reduce: only every-8th lane nonzero -> 3-op DPP chain
// (shr8 + bcast15 + bcast31), result in lane 63.
// ---------------------------------------------------------------------------
__global__ __launch_bounds__(256, 1)
void brnn_recur_xp(const float* __restrict__ xp,
                   const float* __restrict__ Whh_f, const float* __restrict__ Whh_b,
                   const float* __restrict__ weff,  float* __restrict__ partbuf)
{
    const int blk  = blockIdx.x;
    const int dir  = blk >> 6;
    const int b    = blk & 63;
    const int tid  = threadIdx.x;
    const int w    = tid >> 6;
    const int l    = tid & 63;
    const int g    = l & 7;
    const int m    = l >> 3;
    const int j0   = w * 32 + m * 4;
    const bool wr  = (g == 7);

    const float* Whh = dir ? Whh_b : Whh_f;

    float whh[64];
    #pragma unroll
    for (int jj = 0; jj < 4; ++jj)
        #pragma unroll
        for (int i = 0; i < 4; ++i)
            ((float4*)whh)[jj * 4 + i] =
                *(const float4*)(Whh + (j0 + jj) * 128 + g * 16 + i * 4);

    const float4 w4 = *(const float4*)(weff + dir * 128 + j0);

    __shared__ __align__(16) float hbuf[2][160];
    if (tid < 160) hbuf[0][tid] = 0.0f;
    __syncthreads();

    const float* xpbase = xp + ((size_t)(dir * 64 + b)) * T_LEN * H_SZ + j0;
    float* pout = partbuf + ((size_t)blk * 4 + w) * T_LEN;

    float4 xq0, xq1, xq2, xq3;
    xq0 = *(const float4*)(xpbase + (size_t)(dir ? (T_LEN - 1) : 0) * H_SZ);
    xq1 = *(const float4*)(xpbase + (size_t)(dir ? (T_LEN - 2) : 1) * H_SZ);

    float p_carry = 0.0f;
    int   t_prev  = 0;

    const int hwidx = 40 * w + 4 * m + 4 * (m >> 2);

#define STEP(S, RD, XPC, XPN) do {                                             \
        const int s_  = (S);                                                   \
        /* finish previous step's p: sparse 3-op DPP reduce + store */         \
        if (s_ > 0) {                                                          \
            float pr_ = p_carry;                                               \
            DPP_ADD_F32(pr_, 0x118);  /* row_shr:8  -> pairs @15,31,47,63 */   \
            DPP_ADD_F32(pr_, 0x142);  /* row_bcast:15 -> quads @31,63 */       \
            DPP_ADD_F32(pr_, 0x143);  /* row_bcast:31 -> full @63 */           \
            if (l == 63) pout[t_prev] = pr_;                                   \
        }                                                                      \
        /* prefetch xp for step s+2 */                                         \
        {                                                                      \
            const int sp_ = (s_ + 2 < T_LEN) ? (s_ + 2) : (T_LEN - 1);         \
            const int tp_ = dir ? (T_LEN - 1 - sp_) : sp_;                     \
            XPN = *(const float4*)(xpbase + (size_t)tp_ * H_SZ);               \
        }                                                                      \
        /* h reads (4 x b128, conflict-free) */                                \
        const float4* hp_ = (const float4*)&hbuf[RD][20 * g];                  \
        float4 hv_[4];                                                         \
        _Pragma("unroll") for (int i = 0; i < 4; ++i) hv_[i] = hp_[i];         \
        float a0 = (g == 0) ? XPC.x : 0.0f;                                    \
        float a1 = (g == 0) ? XPC.y : 0.0f;                                    \
        float a2 = (g == 0) ? XPC.z : 0.0f;                                    \
        float a3 = (g == 0) ? XPC.w : 0.0f;                                    \
        _Pragma("unroll") for (int i = 0; i < 4; ++i) {                        \
            const float* hq_ = (const float*)&hv_[i];                          \
            _Pragma("unroll") for (int c = 0; c < 4; ++c) {                    \
                a0 = fmaf(whh[0 * 16 + i * 4 + c], hq_[c], a0);                \
                a1 = fmaf(whh[1 * 16 + i * 4 + c], hq_[c], a1);                \
                a2 = fmaf(whh[2 * 16 + i * 4 + c], hq_[c], a2);                \
                a3 = fmaf(whh[3 * 16 + i * 4 + c], hq_[c], a3);                \
            }                                                                  \
        }                                                                      \
        /* sum over the 8-lane k-group: lane 8m+7 accumulates its group */     \
        DPP_ADD_F32(a0, 0x111); DPP_ADD_F32(a1, 0x111);                        \
        DPP_ADD_F32(a2, 0x111); DPP_ADD_F32(a3, 0x111);                        \
        DPP_ADD_F32(a0, 0x112); DPP_ADD_F32(a1, 0x112);                        \
        DPP_ADD_F32(a2, 0x112); DPP_ADD_F32(a3, 0x112);                        \
        DPP_ADD_F32(a0, 0x114); DPP_ADD_F32(a1, 0x114);                        \
        DPP_ADD_F32(a2, 0x114); DPP_ADD_F32(a3, 0x114);                        \
        float4 h4_;                                                            \
        h4_.x = fmaxf(a0, 0.0f); h4_.y = fmaxf(a1, 0.0f);                      \
        h4_.z = fmaxf(a2, 0.0f); h4_.w = fmaxf(a3, 0.0f);                      \
        p_carry = 0.0f;                                                        \
        if (wr) {                                                              \
            *(float4*)&hbuf[(RD) ^ 1][hwidx] = h4_;                            \
            p_carry = w4.x * h4_.x + w4.y * h4_.y                              \
                    + w4.z * h4_.z + w4.w * h4_.w;                             \
        }                                                                      \
        t_prev = dir ? (T_LEN - 1 - s_) : s_;                                  \
        chain_barrier();                                                       \
    } while (0)

    #pragma unroll 1
    for (int s = 0; s < T_LEN; s += 4) {
        STEP(s,     0, xq0, xq2);
        STEP(s + 1, 1, xq1, xq3);
        STEP(s + 2, 0, xq2, xq0);
        STEP(s + 3, 1, xq3, xq1);
    }
#undef STEP

    {
        float pr = p_carry;
        DPP_ADD_F32(pr, 0x118);
        DPP_ADD_F32(pr, 0x142);
        DPP_ADD_F32(pr, 0x143);
        if (l == 63) pout[t_prev] = pr;
    }
}

// ---------------------------------------------------------------------------
// Fallback recurrence (round-4, x in-loop) for small ws_size. Verbatim.
// ---------------------------------------------------------------------------
__global__ __launch_bounds__(256, 1)
void brnn_recur_fb(const float* __restrict__ x,
                   const float* __restrict__ Wih_f, const float* __restrict__ Whh_f,
                   const float* __restrict__ bih_f, const float* __restrict__ bhh_f,
                   const float* __restrict__ Wih_b, const float* __restrict__ Whh_b,
                   const float* __restrict__ bih_b, const float* __restrict__ bhh_b,
                   const float* __restrict__ weff,  float* __restrict__ partbuf)
{
    const int blk  = blockIdx.x;
    const int dir  = blk >> 6;
    const int b    = blk & 63;
    const int tid  = threadIdx.x;
    const int w    = tid >> 6;
    const int l    = tid & 63;
    const int g    = l & 7;
    const int m    = l >> 3;
    const int j0   = w * 32 + m * 4;
    const bool wr  = (g == 7);

    const float* Wih = dir ? Wih_b : Wih_f;
    const float* Whh = dir ? Whh_b : Whh_f;
    const float* bih = dir ? bih_b : bih_f;
    const float* bhh = dir ? bhh_b : bhh_f;

    float whh[64];
    #pragma unroll
    for (int jj = 0; jj < 4; ++jj)
        #pragma unroll
        for (int i = 0; i < 4; ++i)
            ((float4*)whh)[jj * 4 + i] =
                *(const float4*)(Whh + (j0 + jj) * 128 + g * 16 + i * 4);
    float wih[32];
    #pragma unroll
    for (int jj = 0; jj < 4; ++jj)
        #pragma unroll
        for (int i = 0; i < 2; ++i)
            ((float4*)wih)[jj * 2 + i] =
                *(const float4*)(Wih + (j0 + jj) * 64 + g * 8 + i * 4);

    float4 b4 = make_float4(0.f, 0.f, 0.f, 0.f);
    if (g == 0) {
        float4 bi = *(const float4*)(bih + j0);
        float4 bh = *(const float4*)(bhh + j0);
        b4 = make_float4(bi.x + bh.x, bi.y + bh.y, bi.z + bh.z, bi.w + bh.w);
    }
    const float4 w4 = *(const float4*)(weff + dir * 128 + j0);

    __shared__ __align__(16) float hbuf[2][160];
    if (tid < 160) hbuf[0][tid] = 0.0f;
    __syncthreads();

    const float* xbase = x + (size_t)b * T_LEN * D_IN + g * 8;
    float* pout = partbuf + ((size_t)blk * 4 + w) * T_LEN;

    float xq0[8], xq1[8], xq2[8], xq3[8];
    {
        const float4* xp0 = (const float4*)(xbase + (size_t)(dir ? (T_LEN - 1) : 0) * D_IN);
        ((float4*)xq0)[0] = xp0[0];
        ((float4*)xq0)[1] = xp0[1];
        const float4* xp1 = (const float4*)(xbase + (size_t)(dir ? (T_LEN - 2) : 1) * D_IN);
        ((float4*)xq1)[0] = xp1[0];
        ((float4*)xq1)[1] = xp1[1];
    }

    float p_carry = 0.0f;
    int   t_prev  = 0;
    const int hwidx = 40 * w + 4 * m + 4 * (m >> 2);

#define STEP(S, RD, XCUR, XPRE) do {                                           \
        const int s_  = (S);                                                   \
        if (s_ > 0) {                                                          \
            float pr_ = p_carry;                                               \
            DPP_ADD_F32(pr_, 0x118); DPP_ADD_F32(pr_, 0x142);                  \
            DPP_ADD_F32(pr_, 0x143);                                           \
            if (l == 63) pout[t_prev] = pr_;                                   \
        }                                                                      \
        {                                                                      \
            const int sp_ = (s_ + 2 < T_LEN) ? (s_ + 2) : (T_LEN - 1);         \
            const int tp_ = dir ? (T_LEN - 1 - sp_) : sp_;                     \
            const float4* xp_ = (const float4*)(xbase + (size_t)tp_ * D_IN);   \
            ((float4*)XPRE)[0] = xp_[0];                                       \
            ((float4*)XPRE)[1] = xp_[1];                                       \
        }                                                                      \
        const float4* hp_ = (const float4*)&hbuf[RD][20 * g];                  \
        float4 hv_[4];                                                         \
        _Pragma("unroll") for (int i = 0; i < 4; ++i) hv_[i] = hp_[i];         \
        float a0 = b4.x, a1 = b4.y, a2 = b4.z, a3 = b4.w;                      \
        _Pragma("unroll") for (int i = 0; i < 8; ++i) {                        \
            a0 = fmaf(wih[0 * 8 + i], XCUR[i], a0);                            \
            a1 = fmaf(wih[1 * 8 + i], XCUR[i], a1);                            \
            a2 = fmaf(wih[2 * 8 + i], XCUR[i], a2);                            \
            a3 = fmaf(wih[3 * 8 + i], XCUR[i], a3);                            \
        }                                                                      \
        _Pragma("unroll") for (int i = 0; i < 4; ++i) {                        \
            const float* hq_ = (const float*)&hv_[i];                          \
            _Pragma("unroll") for (int c = 0; c < 4; ++c) {                    \
                a0 = fmaf(whh[0 * 16 + i * 4 + c], hq_[c], a0);                \
                a1 = fmaf(whh[1 * 16 + i * 4 + c], hq_[c], a1);                \
                a2 = fmaf(whh[2 * 16 + i * 4 + c], hq_[c], a2);                \
                a3 = fmaf(whh[3 * 16 + i * 4 + c], hq_[c], a3);                \
            }                                                                  \
        }                                                                      \
        DPP_ADD_F32(a0, 0x111); DPP_ADD_F32(a1, 0x111);                        \
        DPP_ADD_F32(a2, 0x111); DPP_ADD_F32(a3, 0x111);                        \
        DPP_ADD_F32(a0, 0x112); DPP_ADD_F32(a1, 0x112);                        \
        DPP_ADD_F32(a2, 0x112); DPP_ADD_F32(a3, 0x112);                        \
        DPP_ADD_F32(a0, 0x114); DPP_ADD_F32(a1, 0x114);                        \
        DPP_ADD_F32(a2, 0x114); DPP_ADD_F32(a3, 0x114);                        \
        float4 h4_;                                                            \
        h4_.x = fmaxf(a0, 0.0f); h4_.y = fmaxf(a1, 0.0f);                      \
        h4_.z = fmaxf(a2, 0.0f); h4_.w = fmaxf(a3, 0.0f);                      \
        p_carry = 0.0f;                                                        \
        if (wr) {                                                              \
            *(float4*)&hbuf[(RD) ^ 1][hwidx] = h4_;                            \
            p_carry = w4.x * h4_.x + w4.y * h4_.y                              \
                    + w4.z * h4_.z + w4.w * h4_.w;                             \
        }                                                                      \
        t_prev = dir ? (T_LEN - 1 - s_) : s_;                                  \
        chain_barrier();                                                       \
    } while (0)

    #pragma unroll 1
    for (int s = 0; s < T_LEN; s += 4) {
        STEP(s,     0, xq0, xq2);
        STEP(s + 1, 1, xq1, xq3);
        STEP(s + 2, 0, xq2, xq0);
        STEP(s + 3, 1, xq3, xq1);
    }
#undef STEP

    {
        float pr = p_carry;
        DPP_ADD_F32(pr, 0x118); DPP_ADD_F32(pr, 0x142); DPP_ADD_F32(pr, 0x143);
        if (l == 63) pout[t_prev] = pr;
    }
}

// ---------------------------------------------------------------------------
// Kernel 3: assemble logits from partials and log-softmax over T per batch.
// ---------------------------------------------------------------------------
__global__ __launch_bounds__(256)
void brnn_lsm(const float* __restrict__ partbuf, const float* __restrict__ ws,
              float* __restrict__ out)
{
    const int b   = blockIdx.x;
    const int tid = threadIdx.x;
    __shared__ float lg[T_LEN];
    __shared__ float red[8];

    const float beff = ws[256];

    float lmax = -3.0e38f;
    for (int t = tid; t < T_LEN; t += 256) {
        float s = beff;
        #pragma unroll
        for (int dw = 0; dw < 8; ++dw) {
            const int dir = dw >> 2, wv = dw & 3;
            s += partbuf[(((size_t)(dir * 64 + b)) * 4 + wv) * T_LEN + t];
        }
        lg[t] = s;
        lmax = fmaxf(lmax, s);
    }
    #pragma unroll
    for (int mm = 1; mm <= 32; mm <<= 1) lmax = fmaxf(lmax, __shfl_xor(lmax, mm));
    if ((tid & 63) == 0) red[tid >> 6] = lmax;
    __syncthreads();
    const float bmax = fmaxf(fmaxf(red[0], red[1]), fmaxf(red[2], red[3]));

    float lsum = 0.0f;
    for (int t = tid; t < T_LEN; t += 256) lsum += expf(lg[t] - bmax);
    #pragma unroll
    for (int mm = 1; mm <= 32; mm <<= 1) lsum += __shfl_xor(lsum, mm);
    if ((tid & 63) == 0) red[4 + (tid >> 6)] = lsum;
    __syncthreads();
    const float lse = bmax + logf(red[4] + red[5] + red[6] + red[7]);

    for (int t = tid; t < T_LEN; t += 256)
        out[(size_t)b * T_LEN + t] = lg[t] - lse;
}

// ---------------------------------------------------------------------------
extern "C" void kernel_launch(void* const* d_in, const int* in_sizes, int n_in,
                              void* d_out, int out_size, void* d_ws, size_t ws_size,
                              hipStream_t stream)
{
    const float* x     = (const float*)d_in[0];
    const float* Wih_f = (const float*)d_in[1];
    const float* Whh_f = (const float*)d_in[2];
    const float* bih_f = (const float*)d_in[3];
    const float* bhh_f = (const float*)d_in[4];
    const float* Wih_b = (const float*)d_in[5];
    const float* Whh_b = (const float*)d_in[6];
    const float* bih_b = (const float*)d_in[7];
    const float* bhh_b = (const float*)d_in[8];
    const float* fc1_W = (const float*)d_in[9];
    const float* fc1_b = (const float*)d_in[10];
    const float* fc2_W = (const float*)d_in[11];
    const float* fc2_b = (const float*)d_in[12];
    float* out = (float*)d_out;

    float* wsf = (float*)d_ws;
    const size_t part_off   = 512;
    const size_t part_elems = (size_t)2 * 64 * 4 * T_LEN;          // 1 Mi floats
    const size_t xp_off     = part_off + part_elems;
    const size_t xp_elems   = (size_t)2 * 64 * T_LEN * H_SZ;       // 32 Mi floats
    float* part = wsf + part_off;
    float* xpbf = wsf + xp_off;
    const bool big_ws = ws_size >= (xp_off + xp_elems) * sizeof(float);

    hipLaunchKernelGGL(prep_kernel, dim3(1), dim3(256), 0, stream,
                       fc1_W, fc1_b, fc2_W, fc2_b, wsf);
    if (big_ws) {
        hipLaunchKernelGGL(xp_gemm, dim3(2048), dim3(128), 0, stream,
                           x, Wih_f, bih_f, bhh_f, Wih_b, bih_b, bhh_b, xpbf);
        hipLaunchKernelGGL(brnn_recur_xp, dim3(128), dim3(256), 0, stream,
                           xpbf, Whh_f, Whh_b, wsf, part);
    } else {
        hipLaunchKernelGGL(brnn_recur_fb, dim3(128), dim3(256), 0, stream,
                           x, Wih_f, Whh_f, bih_f, bhh_f,
                           Wih_b, Whh_b, bih_b, bhh_b, wsf, part);
    }
    hipLaunchKernelGGL(brnn_lsm, dim3(64), dim3(256), 0, stream,
                       part, wsf, out);
}